// Round 5
// baseline (705.578 us; speedup 1.0000x reference)
//
#include <hip/hip_runtime.h>

#define NFEAT 512
#define HID 16
#define MAXNB 512          // max buckets (N/256 = 391 for N=100K)
#define PACK_SHIFT 17      // src fits in 17 bits (N < 131072)

// ============ bucket histogram: bucket = dst >> 8 ============
__global__ __launch_bounds__(256) void k_bcnt(const int* __restrict__ ei,
                                              int* __restrict__ gcnt, int E, int nb) {
  __shared__ int l[MAXNB];
  for (int i = threadIdx.x; i < nb; i += 256) l[i] = 0;
  __syncthreads();
  for (int e = blockIdx.x * 256 + threadIdx.x; e < E; e += gridDim.x * 256)
    atomicAdd(&l[ei[(size_t)E + e] >> 8], 1);
  __syncthreads();
  for (int b = threadIdx.x; b < nb; b += 256)
    if (l[b]) atomicAdd(&gcnt[b], l[b]);
}

// ============ scan: 16-aligned bucket bases + cursors ============
__global__ __launch_bounds__(512) void k_bscan(const int* __restrict__ gcnt,
                                               int* __restrict__ gbase,
                                               int* __restrict__ gcur, int nb) {
  __shared__ int sm[512];
  int t = threadIdx.x;
  int c = (t < nb) ? gcnt[t] : 0;
  int pc = (c + 15) & ~15;  // pad each bucket region to 16-entry alignment
  sm[t] = pc;
  __syncthreads();
  for (int off = 1; off < 512; off <<= 1) {
    int x = (t >= off) ? sm[t - off] : 0;
    __syncthreads();
    sm[t] += x;
    __syncthreads();
  }
  if (t < nb) {
    int excl = sm[t] - pc;
    gbase[t] = excl;
    gcur[t] = excl;
  }
}

// ============ binning scatter with LDS line staging ============
// Full 16-entry (64B) lines flushed per global-cursor bump -> no write amplification.
__global__ __launch_bounds__(512) void k_binscatter(const int* __restrict__ ei,
                                                    int* __restrict__ gcur,
                                                    int* __restrict__ binned,
                                                    int E, int nb) {
  __shared__ int stage[MAXNB][16];
  __shared__ int scnt[MAXNB];
  for (int i = threadIdx.x; i < nb; i += 512) scnt[i] = 0;
  __syncthreads();

  int chunk = (E + gridDim.x - 1) / gridDim.x;
  int beg = blockIdx.x * chunk;
  int end = beg + chunk; if (end > E) end = E;

  for (int r = beg; r < end; r += 512) {
    int e = r + threadIdx.x;
    bool have = e < end;
    int val = 0, b = 0;
    if (have) {
      int s = ei[e];
      int d = ei[(size_t)E + e];
      b = d >> 8;
      val = s | ((d & 255) << PACK_SHIFT);
      int pos = atomicAdd(&scnt[b], 1);
      if (pos < 16) stage[b][pos] = val;
      else binned[atomicAdd(&gcur[b], 1)] = val;  // rare overflow spill
    }
    __syncthreads();
    // flush full lines
    for (int b2 = threadIdx.x; b2 < nb; b2 += 512) {
      if (scnt[b2] >= 16) {
        int g = atomicAdd(&gcur[b2], 16);
#pragma unroll
        for (int q = 0; q < 16; q++) binned[g + q] = stage[b2][q];
        scnt[b2] = 0;
      }
    }
    __syncthreads();
  }
  // final partial flush
  for (int b2 = threadIdx.x; b2 < nb; b2 += 512) {
    int c = scnt[b2];
    if (c > 0) {
      int g = atomicAdd(&gcur[b2], c);
      for (int q = 0; q < c; q++) binned[g + q] = stage[b2][q];
    }
  }
}

// ============ per-bucket degree histogram -> dinv ============
__global__ __launch_bounds__(256) void k_degb(const int* __restrict__ gbase,
                                              const int* __restrict__ gcnt,
                                              const int* __restrict__ binned,
                                              float* __restrict__ dinv, int N) {
  __shared__ int hist[256];
  hist[threadIdx.x] = 0;
  __syncthreads();
  int b = blockIdx.x;
  int base = gbase[b], cnt = gcnt[b];
  for (int j = base + threadIdx.x; j < base + cnt; j += 256)
    atomicAdd(&hist[binned[j] >> PACK_SHIFT], 1);
  __syncthreads();
  int node = b * 256 + threadIdx.x;
  if (node < N) dinv[node] = rsqrtf((float)hist[threadIdx.x] + 1.0f);
}

// ============ GEMM1: h1s = (x @ W1) * dinv[row] ============
#define KC 16
#define NC (NFEAT / KC)
#define XPAD 20

__device__ __forceinline__ void fma4(float4& a, float s, const float4& b) {
  a.x += s * b.x;
  a.y += s * b.y;
  a.z += s * b.z;
  a.w += s * b.w;
}

__global__ __launch_bounds__(256) void k_gemm1(const float* __restrict__ x,
                                               const float* __restrict__ W,
                                               const float* __restrict__ dinv,
                                               float* __restrict__ h1s, int N) {
  __shared__ float sW[NFEAT * HID];  // 32 KB
  __shared__ float sx[256][XPAD];    // 20 KB
  float4* sW4 = (float4*)sW;
  const float4* W4 = (const float4*)W;
  for (int i = threadIdx.x; i < NFEAT * HID / 4; i += 256) sW4[i] = W4[i];

  const float4* x4 = (const float4*)x;
  const int row0 = blockIdx.x * 256;
  const int Nm1 = N - 1;
  const int jq = threadIdx.x & 3;
  const int rg = threadIdx.x >> 2;

  float4 acc[4];
#pragma unroll
  for (int m = 0; m < 4; m++) acc[m] = make_float4(0.f, 0.f, 0.f, 0.f);

  float4 ld[4];
#pragma unroll
  for (int i = 0; i < 4; i++) {
    int f = threadIdx.x + (i << 8);
    int r = f >> 2, k4 = f & 3;
    int rr = row0 + r; if (rr > Nm1) rr = Nm1;
    ld[i] = x4[(size_t)rr * (NFEAT / 4) + k4];
  }

  for (int c = 0; c < NC; ++c) {
#pragma unroll
    for (int i = 0; i < 4; i++) {
      int f = threadIdx.x + (i << 8);
      int r = f >> 2, k4 = f & 3;
      *(float4*)&sx[r][k4 << 2] = ld[i];
    }
    __syncthreads();
    if (c + 1 < NC) {
#pragma unroll
      for (int i = 0; i < 4; i++) {
        int f = threadIdx.x + (i << 8);
        int r = f >> 2, k4 = f & 3;
        int rr = row0 + r; if (rr > Nm1) rr = Nm1;
        ld[i] = x4[(size_t)rr * (NFEAT / 4) + (c + 1) * (KC / 4) + k4];
      }
    }
#pragma unroll
    for (int q = 0; q < KC / 4; q++) {
      int k0 = c * KC + q * 4;
      float4 w0 = sW4[(k0 + 0) * 4 + jq];
      float4 w1 = sW4[(k0 + 1) * 4 + jq];
      float4 w2 = sW4[(k0 + 2) * 4 + jq];
      float4 w3 = sW4[(k0 + 3) * 4 + jq];
#pragma unroll
      for (int m = 0; m < 4; m++) {
        float4 xv = *(const float4*)&sx[rg + (m << 6)][q << 2];
        fma4(acc[m], xv.x, w0);
        fma4(acc[m], xv.y, w1);
        fma4(acc[m], xv.z, w2);
        fma4(acc[m], xv.w, w3);
      }
    }
    __syncthreads();
  }

#pragma unroll
  for (int m = 0; m < 4; m++) {
    int r = row0 + rg + (m << 6);
    if (r < N) {
      float di = dinv[r];
      acc[m].x *= di; acc[m].y *= di; acc[m].z *= di; acc[m].w *= di;
      *(float4*)&h1s[(size_t)r * HID + (jq << 2)] = acc[m];
    }
  }
}

// ===== layer1: per-bucket LDS accumulate + relu + W2 -> h2s =====
// h2s[n] = dinv[n] * ( relu( dinv[n]*(h1s[n] + sum_src h1s[src]) + b1 ) @ W2 )
__global__ __launch_bounds__(256) void k_agg1b(const int* __restrict__ gbase,
                                               const int* __restrict__ gcnt,
                                               const int* __restrict__ binned,
                                               const float* __restrict__ h1s,
                                               const float* __restrict__ dinv,
                                               const float* __restrict__ b1,
                                               const float* __restrict__ W2,
                                               float* __restrict__ h2s, int N) {
  __shared__ float acc[256][HID + 1];  // +1 pad: epilogue reads row-serial
  const int b = blockIdx.x;
  const int f = threadIdx.x & 15;
  const int eg = threadIdx.x >> 4;  // 16 edge groups
  // init with self-loop term (f-major: coalesced 64B per 16-lane group)
  for (int i = eg; i < 256; i += 16) {
    int node = b * 256 + i;
    acc[i][f] = (node < N) ? h1s[(size_t)node * HID + f] : 0.f;
  }
  __syncthreads();
  const int base = gbase[b], cnt = gcnt[b];
  for (int j = base + eg; j < base + cnt; j += 16) {
    int val = binned[j];
    int s = val & ((1 << PACK_SHIFT) - 1);
    int dl = val >> PACK_SHIFT;
    atomicAdd(&acc[dl][f], h1s[(size_t)s * HID + f]);
  }
  __syncthreads();
  int node = b * 256 + threadIdx.x;
  if (node < N) {
    float di = dinv[node];
    float o0 = 0.f, o1 = 0.f;
#pragma unroll
    for (int q = 0; q < HID; q++) {
      float v = fmaxf(acc[threadIdx.x][q] * di + b1[q], 0.f);
      o0 += v * W2[q * 2 + 0];
      o1 += v * W2[q * 2 + 1];
    }
    *(float2*)&h2s[(size_t)node * 2] = make_float2(o0 * di, o1 * di);
  }
}

// ===== layer2: per-bucket LDS accumulate + bias -> out =====
__global__ __launch_bounds__(256) void k_agg2b(const int* __restrict__ gbase,
                                               const int* __restrict__ gcnt,
                                               const int* __restrict__ binned,
                                               const float* __restrict__ h2s,
                                               const float* __restrict__ dinv,
                                               const float* __restrict__ b2,
                                               float* __restrict__ out, int N) {
  __shared__ float acc2[256][2];
  const int b = blockIdx.x;
  {
    int node = b * 256 + threadIdx.x;
    float2 self = (node < N) ? *(const float2*)&h2s[(size_t)node * 2]
                             : make_float2(0.f, 0.f);
    acc2[threadIdx.x][0] = self.x;
    acc2[threadIdx.x][1] = self.y;
  }
  __syncthreads();
  const int base = gbase[b], cnt = gcnt[b];
  for (int j = base + threadIdx.x; j < base + cnt; j += 256) {
    int val = binned[j];
    int s = val & ((1 << PACK_SHIFT) - 1);
    int dl = val >> PACK_SHIFT;
    float2 v = *(const float2*)&h2s[(size_t)s * 2];
    atomicAdd(&acc2[dl][0], v.x);
    atomicAdd(&acc2[dl][1], v.y);
  }
  __syncthreads();
  int node = b * 256 + threadIdx.x;
  if (node < N) {
    float di = dinv[node];
    float2 o;
    o.x = acc2[threadIdx.x][0] * di + b2[0];
    o.y = acc2[threadIdx.x][1] * di + b2[1];
    *(float2*)&out[(size_t)node * 2] = o;
  }
}

// ================= launch =================
extern "C" void kernel_launch(void* const* d_in, const int* in_sizes, int n_in,
                              void* d_out, int out_size, void* d_ws, size_t ws_size,
                              hipStream_t stream) {
  const float* x = (const float*)d_in[0];
  const int* ei = (const int*)d_in[1];  // harness delivers integer inputs as int32
  const float* W1 = (const float*)d_in[2];
  const float* b1 = (const float*)d_in[3];
  const float* W2 = (const float*)d_in[4];
  const float* b2 = (const float*)d_in[5];
  float* out = (float*)d_out;
  const int N = in_sizes[0] / NFEAT;
  const int E = in_sizes[1] / 2;
  const int nb = (N + 255) / 256;  // buckets of 256 nodes

  // workspace: gcnt[nb] gbase[nb] gcur[nb] binned[E + MAXNB*16] (ints)
  //            dinv[N] h1s[16N] h2s[2N] (floats)   ~20.2 MB
  char* p = (char*)d_ws;
  int* gcnt = (int*)p;     p += (size_t)MAXNB * 4;
  int* gbase = (int*)p;    p += (size_t)MAXNB * 4;
  int* gcur = (int*)p;     p += (size_t)MAXNB * 4;
  int* binned = (int*)p;   p += ((size_t)E + MAXNB * 16) * 4;
  float* dinv = (float*)p; p += (size_t)N * 4;
  float* h1s = (float*)p;  p += (size_t)N * HID * 4;
  float* h2s = (float*)p;  p += (size_t)N * 2 * 4;

  (void)hipMemsetAsync(gcnt, 0, (size_t)nb * sizeof(int), stream);
  k_bcnt<<<256, 256, 0, stream>>>(ei, gcnt, E, nb);
  k_bscan<<<1, 512, 0, stream>>>(gcnt, gbase, gcur, nb);
  k_binscatter<<<128, 512, 0, stream>>>(ei, gcur, binned, E, nb);
  k_degb<<<nb, 256, 0, stream>>>(gbase, gcnt, binned, dinv, N);
  k_gemm1<<<(N + 255) / 256, 256, 0, stream>>>(x, W1, dinv, h1s, N);
  k_agg1b<<<nb, 256, 0, stream>>>(gbase, gcnt, binned, h1s, dinv, b1, W2, h2s, N);
  k_agg2b<<<nb, 256, 0, stream>>>(gbase, gcnt, binned, h2s, dinv, b2, out, N);
}

// Round 6
// 394.142 us; speedup vs baseline: 1.7902x; 1.7902x over previous
//
#include <hip/hip_runtime.h>

#define NFEAT 512
#define HID 16
#define MAXNB 512          // max buckets (N/256 = 391 for N=100K)
#define PACK_SHIFT 17      // src fits in 17 bits (N < 131072)
#define PACK_MASK ((1 << PACK_SHIFT) - 1)

// ============ bucket histogram: bucket = dst >> 8 ============
__global__ __launch_bounds__(256) void k_bcnt(const int* __restrict__ ei,
                                              int* __restrict__ gcnt, int E, int nb) {
  __shared__ int l[MAXNB];
  for (int i = threadIdx.x; i < nb; i += 256) l[i] = 0;
  __syncthreads();
  for (int e = blockIdx.x * 256 + threadIdx.x; e < E; e += gridDim.x * 256)
    atomicAdd(&l[ei[(size_t)E + e] >> 8], 1);
  __syncthreads();
  for (int b = threadIdx.x; b < nb; b += 256)
    if (l[b]) atomicAdd(&gcnt[b], l[b]);
}

// ============ scan: 16-aligned bucket bases + cursors ============
__global__ __launch_bounds__(512) void k_bscan(const int* __restrict__ gcnt,
                                               int* __restrict__ gbase,
                                               int* __restrict__ gcur, int nb) {
  __shared__ int sm[512];
  int t = threadIdx.x;
  int c = (t < nb) ? gcnt[t] : 0;
  int pc = (c + 15) & ~15;  // pad each bucket region to 16-entry alignment
  sm[t] = pc;
  __syncthreads();
  for (int off = 1; off < 512; off <<= 1) {
    int x = (t >= off) ? sm[t - off] : 0;
    __syncthreads();
    sm[t] += x;
    __syncthreads();
  }
  if (t < nb) {
    int excl = sm[t] - pc;
    gbase[t] = excl;
    gcur[t] = excl;
  }
}

// ============ binning scatter with LDS line staging ============
__global__ __launch_bounds__(512) void k_binscatter(const int* __restrict__ ei,
                                                    int* __restrict__ gcur,
                                                    int* __restrict__ binned,
                                                    int E, int nb) {
  __shared__ int stage[MAXNB][16];
  __shared__ int scnt[MAXNB];
  for (int i = threadIdx.x; i < nb; i += 512) scnt[i] = 0;
  __syncthreads();

  int chunk = (E + gridDim.x - 1) / gridDim.x;
  int beg = blockIdx.x * chunk;
  int end = beg + chunk; if (end > E) end = E;

  for (int r = beg; r < end; r += 512) {
    int e = r + threadIdx.x;
    if (e < end) {
      int s = ei[e];
      int d = ei[(size_t)E + e];
      int b = d >> 8;
      int val = s | ((d & 255) << PACK_SHIFT);
      int pos = atomicAdd(&scnt[b], 1);
      if (pos < 16) stage[b][pos] = val;
      else binned[atomicAdd(&gcur[b], 1)] = val;  // rare overflow spill
    }
    __syncthreads();
    for (int b2 = threadIdx.x; b2 < nb; b2 += 512) {
      if (scnt[b2] >= 16) {
        int g = atomicAdd(&gcur[b2], 16);
#pragma unroll
        for (int q = 0; q < 16; q++) binned[g + q] = stage[b2][q];
        scnt[b2] = 0;
      }
    }
    __syncthreads();
  }
  for (int b2 = threadIdx.x; b2 < nb; b2 += 512) {
    int c = scnt[b2];
    if (c > 0) {
      int g = atomicAdd(&gcur[b2], c);
      for (int q = 0; q < c; q++) binned[g + q] = stage[b2][q];
    }
  }
}

// ============ per-bucket sort -> per-node CSR + dinv ============
// Scatter stays within a 32KB L2 window per block -> writes combine in L2.
__global__ __launch_bounds__(256) void k_sortbucket(const int* __restrict__ gbase,
                                                    const int* __restrict__ gcnt,
                                                    const int* __restrict__ binned,
                                                    int* __restrict__ csr,
                                                    int* __restrict__ rowbeg,
                                                    int* __restrict__ rowend,
                                                    float* __restrict__ dinv, int N) {
  __shared__ int hist[256];
  __shared__ int sm[256];
  __shared__ int cur[256];
  const int t = threadIdx.x;
  const int b = blockIdx.x;
  const int base = gbase[b], cnt = gcnt[b];
  hist[t] = 0;
  __syncthreads();
  for (int j = base + t; j < base + cnt; j += 256)
    atomicAdd(&hist[binned[j] >> PACK_SHIFT], 1);
  __syncthreads();
  int h = hist[t];
  sm[t] = h;
  __syncthreads();
  for (int off = 1; off < 256; off <<= 1) {
    int x = (t >= off) ? sm[t - off] : 0;
    __syncthreads();
    sm[t] += x;
    __syncthreads();
  }
  int incl = sm[t];
  int excl = incl - h;
  cur[t] = excl;
  int node = b * 256 + t;
  if (node < N) {
    rowbeg[node] = base + excl;
    rowend[node] = base + incl;
    dinv[node] = rsqrtf((float)h + 1.0f);
  }
  __syncthreads();
  for (int j = base + t; j < base + cnt; j += 256) {
    int val = binned[j];
    int pos = atomicAdd(&cur[val >> PACK_SHIFT], 1);
    csr[base + pos] = val & PACK_MASK;
  }
}

// ============ GEMM1: h1s = (x @ W1) * dinv[row] ============
#define KC 16
#define NC (NFEAT / KC)
#define XPAD 20

__device__ __forceinline__ void fma4(float4& a, float s, const float4& b) {
  a.x += s * b.x;
  a.y += s * b.y;
  a.z += s * b.z;
  a.w += s * b.w;
}

__global__ __launch_bounds__(256) void k_gemm1(const float* __restrict__ x,
                                               const float* __restrict__ W,
                                               const float* __restrict__ dinv,
                                               float* __restrict__ h1s, int N) {
  __shared__ float sW[NFEAT * HID];  // 32 KB
  __shared__ float sx[256][XPAD];    // 20 KB
  float4* sW4 = (float4*)sW;
  const float4* W4 = (const float4*)W;
  for (int i = threadIdx.x; i < NFEAT * HID / 4; i += 256) sW4[i] = W4[i];

  const float4* x4 = (const float4*)x;
  const int row0 = blockIdx.x * 256;
  const int Nm1 = N - 1;
  const int jq = threadIdx.x & 3;
  const int rg = threadIdx.x >> 2;

  float4 acc[4];
#pragma unroll
  for (int m = 0; m < 4; m++) acc[m] = make_float4(0.f, 0.f, 0.f, 0.f);

  float4 ld[4];
#pragma unroll
  for (int i = 0; i < 4; i++) {
    int f = threadIdx.x + (i << 8);
    int r = f >> 2, k4 = f & 3;
    int rr = row0 + r; if (rr > Nm1) rr = Nm1;
    ld[i] = x4[(size_t)rr * (NFEAT / 4) + k4];
  }

  for (int c = 0; c < NC; ++c) {
#pragma unroll
    for (int i = 0; i < 4; i++) {
      int f = threadIdx.x + (i << 8);
      int r = f >> 2, k4 = f & 3;
      *(float4*)&sx[r][k4 << 2] = ld[i];
    }
    __syncthreads();
    if (c + 1 < NC) {
#pragma unroll
      for (int i = 0; i < 4; i++) {
        int f = threadIdx.x + (i << 8);
        int r = f >> 2, k4 = f & 3;
        int rr = row0 + r; if (rr > Nm1) rr = Nm1;
        ld[i] = x4[(size_t)rr * (NFEAT / 4) + (c + 1) * (KC / 4) + k4];
      }
    }
#pragma unroll
    for (int q = 0; q < KC / 4; q++) {
      int k0 = c * KC + q * 4;
      float4 w0 = sW4[(k0 + 0) * 4 + jq];
      float4 w1 = sW4[(k0 + 1) * 4 + jq];
      float4 w2 = sW4[(k0 + 2) * 4 + jq];
      float4 w3 = sW4[(k0 + 3) * 4 + jq];
#pragma unroll
      for (int m = 0; m < 4; m++) {
        float4 xv = *(const float4*)&sx[rg + (m << 6)][q << 2];
        fma4(acc[m], xv.x, w0);
        fma4(acc[m], xv.y, w1);
        fma4(acc[m], xv.z, w2);
        fma4(acc[m], xv.w, w3);
      }
    }
    __syncthreads();
  }

#pragma unroll
  for (int m = 0; m < 4; m++) {
    int r = row0 + rg + (m << 6);
    if (r < N) {
      float di = dinv[r];
      acc[m].x *= di; acc[m].y *= di; acc[m].z *= di; acc[m].w *= di;
      *(float4*)&h1s[(size_t)r * HID + (jq << 2)] = acc[m];
    }
  }
}

// ===== layer1 aggregation + relu + W2, fused. 16 lanes per node. =====
__global__ __launch_bounds__(256) void k_agg1f(const int* __restrict__ rowbeg,
                                               const int* __restrict__ rowend,
                                               const int* __restrict__ csr,
                                               const float* __restrict__ h1s,
                                               const float* __restrict__ dinv,
                                               const float* __restrict__ b1,
                                               const float* __restrict__ W2,
                                               float* __restrict__ h2s, int N) {
  const int f = threadIdx.x & 15;
  const int node = blockIdx.x * 16 + (threadIdx.x >> 4);
  if (node >= N) return;
  int j = rowbeg[node];
  const int end = rowend[node];
  float acc = h1s[(size_t)node * HID + f];  // self loop (pre-scaled)
  // align j to 4 for int4 loads
  for (; j < end && (j & 3); ++j) acc += h1s[(size_t)csr[j] * HID + f];
  for (; j + 4 <= end; j += 4) {
    int4 ss = *(const int4*)&csr[j];  // broadcast within group
    float a0 = h1s[(size_t)ss.x * HID + f];
    float a1 = h1s[(size_t)ss.y * HID + f];
    float a2 = h1s[(size_t)ss.z * HID + f];
    float a3 = h1s[(size_t)ss.w * HID + f];
    acc += (a0 + a1) + (a2 + a3);
  }
  for (; j < end; ++j) acc += h1s[(size_t)csr[j] * HID + f];

  float di = dinv[node];
  float v = fmaxf(acc * di + b1[f], 0.f);
  float o0 = v * W2[f * 2 + 0];
  float o1 = v * W2[f * 2 + 1];
#pragma unroll
  for (int d = 1; d < 16; d <<= 1) {
    o0 += __shfl_xor(o0, d);
    o1 += __shfl_xor(o1, d);
  }
  if (f == 0) *(float2*)&h2s[(size_t)node * 2] = make_float2(o0 * di, o1 * di);
}

// ===== layer2 aggregation + bias, fused. thread per node. =====
__global__ __launch_bounds__(256) void k_agg2f(const int* __restrict__ rowbeg,
                                               const int* __restrict__ rowend,
                                               const int* __restrict__ csr,
                                               const float* __restrict__ h2s,
                                               const float* __restrict__ dinv,
                                               const float* __restrict__ b2,
                                               float* __restrict__ out, int N) {
  int i = blockIdx.x * 256 + threadIdx.x;
  if (i >= N) return;
  int j = rowbeg[i];
  const int end = rowend[i];
  float2 o = *(const float2*)&h2s[(size_t)i * 2];  // self loop
  for (; j < end && (j & 3); ++j) {
    float2 v = *(const float2*)&h2s[(size_t)csr[j] * 2];
    o.x += v.x; o.y += v.y;
  }
  for (; j + 4 <= end; j += 4) {
    int4 ss = *(const int4*)&csr[j];
    float2 v0 = *(const float2*)&h2s[(size_t)ss.x * 2];
    float2 v1 = *(const float2*)&h2s[(size_t)ss.y * 2];
    float2 v2 = *(const float2*)&h2s[(size_t)ss.z * 2];
    float2 v3 = *(const float2*)&h2s[(size_t)ss.w * 2];
    o.x += (v0.x + v1.x) + (v2.x + v3.x);
    o.y += (v0.y + v1.y) + (v2.y + v3.y);
  }
  for (; j < end; ++j) {
    float2 v = *(const float2*)&h2s[(size_t)csr[j] * 2];
    o.x += v.x; o.y += v.y;
  }
  float di = dinv[i];
  o.x = o.x * di + b2[0];
  o.y = o.y * di + b2[1];
  *(float2*)&out[(size_t)i * 2] = o;
}

// ================= launch =================
extern "C" void kernel_launch(void* const* d_in, const int* in_sizes, int n_in,
                              void* d_out, int out_size, void* d_ws, size_t ws_size,
                              hipStream_t stream) {
  const float* x = (const float*)d_in[0];
  const int* ei = (const int*)d_in[1];  // harness delivers integer inputs as int32
  const float* W1 = (const float*)d_in[2];
  const float* b1 = (const float*)d_in[3];
  const float* W2 = (const float*)d_in[4];
  const float* b2 = (const float*)d_in[5];
  float* out = (float*)d_out;
  const int N = in_sizes[0] / NFEAT;
  const int E = in_sizes[1] / 2;
  const int nb = (N + 255) / 256;  // buckets of 256 nodes

  // workspace: gcnt/gbase/gcur[MAXNB], binned[E+pad], csr[E+pad],
  //            rowbeg[N], rowend[N] (ints); dinv[N], h1s[16N], h2s[2N] (floats)
  //            total ~35 MB
  char* p = (char*)d_ws;
  int* gcnt = (int*)p;     p += (size_t)MAXNB * 4;
  int* gbase = (int*)p;    p += (size_t)MAXNB * 4;
  int* gcur = (int*)p;     p += (size_t)MAXNB * 4;
  int* binned = (int*)p;   p += ((size_t)E + MAXNB * 16) * 4;
  int* csr = (int*)p;      p += ((size_t)E + MAXNB * 16) * 4;
  int* rowbeg = (int*)p;   p += (size_t)N * 4;
  int* rowend = (int*)p;   p += (size_t)N * 4;
  float* dinv = (float*)p; p += (size_t)N * 4;
  float* h1s = (float*)p;  p += (size_t)N * HID * 4;
  float* h2s = (float*)p;  p += (size_t)N * 2 * 4;

  (void)hipMemsetAsync(gcnt, 0, (size_t)nb * sizeof(int), stream);
  k_bcnt<<<256, 256, 0, stream>>>(ei, gcnt, E, nb);
  k_bscan<<<1, 512, 0, stream>>>(gcnt, gbase, gcur, nb);
  k_binscatter<<<128, 512, 0, stream>>>(ei, gcur, binned, E, nb);
  k_sortbucket<<<nb, 256, 0, stream>>>(gbase, gcnt, binned, csr, rowbeg, rowend, dinv, N);
  k_gemm1<<<(N + 255) / 256, 256, 0, stream>>>(x, W1, dinv, h1s, N);
  k_agg1f<<<(N + 15) / 16, 256, 0, stream>>>(rowbeg, rowend, csr, h1s, dinv, b1, W2, h2s, N);
  k_agg2f<<<(N + 255) / 256, 256, 0, stream>>>(rowbeg, rowend, csr, h2s, dinv, b2, out, N);
}

// Round 7
// 244.372 us; speedup vs baseline: 2.8873x; 1.6129x over previous
//
#include <hip/hip_runtime.h>

#define NFEAT 512
#define HID 16
#define MAXNB 512          // max buckets (N/256 = 391 for N=100K)
#define NBLK 256           // blocks for hist/scatter passes (chunking must match)
#define PACK_SHIFT 17      // src fits in 17 bits (N < 131072)
#define PACK_MASK ((1 << PACK_SHIFT) - 1)

// ============ pass A: per-(block,bucket) histogram ============
__global__ __launch_bounds__(512) void k_hist2d(const int* __restrict__ ei,
                                                int* __restrict__ cnt_t,
                                                int E, int nb) {
  __shared__ int l[MAXNB];
  for (int i = threadIdx.x; i < nb; i += 512) l[i] = 0;
  __syncthreads();
  int chunk = (E + NBLK - 1) / NBLK;
  int beg = blockIdx.x * chunk;
  int end = beg + chunk; if (end > E) end = E;
  for (int e = beg + threadIdx.x; e < end; e += 512)
    atomicAdd(&l[ei[(size_t)E + e] >> 8], 1);
  __syncthreads();
  for (int b = threadIdx.x; b < nb; b += 512)
    cnt_t[(size_t)b * NBLK + blockIdx.x] = l[b];
}

// ============ per-bucket column scan (one wave per bucket) ============
__global__ __launch_bounds__(64) void k_colscan(const int* __restrict__ cnt_t,
                                                int* __restrict__ off_t,
                                                int* __restrict__ gcnt, int nb) {
  int b = blockIdx.x;
  if (b >= nb) return;
  int lane = threadIdx.x;
  int4 v = *(const int4*)&cnt_t[(size_t)b * NBLK + lane * 4];
  int tot = v.x + v.y + v.z + v.w;
  int s = tot;
  for (int d = 1; d < 64; d <<= 1) {
    int o = __shfl_up(s, d);
    if (lane >= d) s += o;
  }
  int excl = s - tot;
  int4 w;
  w.x = excl;
  w.y = excl + v.x;
  w.z = excl + v.x + v.y;
  w.w = excl + v.x + v.y + v.z;
  *(int4*)&off_t[(size_t)b * NBLK + lane * 4] = w;
  if (lane == 63) gcnt[b] = s;
}

// ============ scan: 16-aligned bucket bases ============
__global__ __launch_bounds__(512) void k_bscan(const int* __restrict__ gcnt,
                                               int* __restrict__ gbase, int nb) {
  __shared__ int sm[512];
  int t = threadIdx.x;
  int c = (t < nb) ? gcnt[t] : 0;
  int pc = (c + 15) & ~15;
  sm[t] = pc;
  __syncthreads();
  for (int off = 1; off < 512; off <<= 1) {
    int x = (t >= off) ? sm[t - off] : 0;
    __syncthreads();
    sm[t] += x;
    __syncthreads();
  }
  if (t < nb) gbase[t] = sm[t] - pc;
}

// ============ pass B: scatter with precomputed deterministic offsets ============
// Each block's active write set = <=391 cache lines (25KB) -> L2-combined.
__global__ __launch_bounds__(512) void k_scatter2(const int* __restrict__ ei,
                                                  const int* __restrict__ gbase,
                                                  const int* __restrict__ off_t,
                                                  int* __restrict__ binned,
                                                  int E, int nb) {
  __shared__ int cur[MAXNB];
  for (int b = threadIdx.x; b < nb; b += 512)
    cur[b] = gbase[b] + off_t[(size_t)b * NBLK + blockIdx.x];
  __syncthreads();
  int chunk = (E + NBLK - 1) / NBLK;
  int beg = blockIdx.x * chunk;
  int end = beg + chunk; if (end > E) end = E;
  for (int e = beg + threadIdx.x; e < end; e += 512) {
    int s = ei[e];
    int d = ei[(size_t)E + e];
    int b = d >> 8;
    int pos = atomicAdd(&cur[b], 1);
    binned[pos] = s | ((d & 255) << PACK_SHIFT);
  }
}

// ============ per-bucket sort -> per-node CSR + dinv ============
__global__ __launch_bounds__(256) void k_sortbucket(const int* __restrict__ gbase,
                                                    const int* __restrict__ gcnt,
                                                    const int* __restrict__ binned,
                                                    int* __restrict__ csr,
                                                    int* __restrict__ rowbeg,
                                                    int* __restrict__ rowend,
                                                    float* __restrict__ dinv, int N) {
  __shared__ int hist[256];
  __shared__ int sm[256];
  __shared__ int cur[256];
  const int t = threadIdx.x;
  const int b = blockIdx.x;
  const int base = gbase[b], cnt = gcnt[b];
  hist[t] = 0;
  __syncthreads();
  for (int j = base + t; j < base + cnt; j += 256)
    atomicAdd(&hist[binned[j] >> PACK_SHIFT], 1);
  __syncthreads();
  int h = hist[t];
  sm[t] = h;
  __syncthreads();
  for (int off = 1; off < 256; off <<= 1) {
    int x = (t >= off) ? sm[t - off] : 0;
    __syncthreads();
    sm[t] += x;
    __syncthreads();
  }
  int incl = sm[t];
  int excl = incl - h;
  cur[t] = excl;
  int node = b * 256 + t;
  if (node < N) {
    rowbeg[node] = base + excl;
    rowend[node] = base + incl;
    dinv[node] = rsqrtf((float)h + 1.0f);
  }
  __syncthreads();
  for (int j = base + t; j < base + cnt; j += 256) {
    int val = binned[j];
    int pos = atomicAdd(&cur[val >> PACK_SHIFT], 1);
    csr[base + pos] = val & PACK_MASK;
  }
}

// ============ GEMM1: h1s = (x @ W1) * dinv[row] ============
#define KC 16
#define NC (NFEAT / KC)
#define XPAD 20

__device__ __forceinline__ void fma4(float4& a, float s, const float4& b) {
  a.x += s * b.x;
  a.y += s * b.y;
  a.z += s * b.z;
  a.w += s * b.w;
}

__global__ __launch_bounds__(256) void k_gemm1(const float* __restrict__ x,
                                               const float* __restrict__ W,
                                               const float* __restrict__ dinv,
                                               float* __restrict__ h1s, int N) {
  __shared__ float sW[NFEAT * HID];  // 32 KB
  __shared__ float sx[256][XPAD];    // 20 KB
  float4* sW4 = (float4*)sW;
  const float4* W4 = (const float4*)W;
  for (int i = threadIdx.x; i < NFEAT * HID / 4; i += 256) sW4[i] = W4[i];

  const float4* x4 = (const float4*)x;
  const int row0 = blockIdx.x * 256;
  const int Nm1 = N - 1;
  const int jq = threadIdx.x & 3;
  const int rg = threadIdx.x >> 2;

  float4 acc[4];
#pragma unroll
  for (int m = 0; m < 4; m++) acc[m] = make_float4(0.f, 0.f, 0.f, 0.f);

  float4 ld[4];
#pragma unroll
  for (int i = 0; i < 4; i++) {
    int f = threadIdx.x + (i << 8);
    int r = f >> 2, k4 = f & 3;
    int rr = row0 + r; if (rr > Nm1) rr = Nm1;
    ld[i] = x4[(size_t)rr * (NFEAT / 4) + k4];
  }

  for (int c = 0; c < NC; ++c) {
#pragma unroll
    for (int i = 0; i < 4; i++) {
      int f = threadIdx.x + (i << 8);
      int r = f >> 2, k4 = f & 3;
      *(float4*)&sx[r][k4 << 2] = ld[i];
    }
    __syncthreads();
    if (c + 1 < NC) {
#pragma unroll
      for (int i = 0; i < 4; i++) {
        int f = threadIdx.x + (i << 8);
        int r = f >> 2, k4 = f & 3;
        int rr = row0 + r; if (rr > Nm1) rr = Nm1;
        ld[i] = x4[(size_t)rr * (NFEAT / 4) + (c + 1) * (KC / 4) + k4];
      }
    }
#pragma unroll
    for (int q = 0; q < KC / 4; q++) {
      int k0 = c * KC + q * 4;
      float4 w0 = sW4[(k0 + 0) * 4 + jq];
      float4 w1 = sW4[(k0 + 1) * 4 + jq];
      float4 w2 = sW4[(k0 + 2) * 4 + jq];
      float4 w3 = sW4[(k0 + 3) * 4 + jq];
#pragma unroll
      for (int m = 0; m < 4; m++) {
        float4 xv = *(const float4*)&sx[rg + (m << 6)][q << 2];
        fma4(acc[m], xv.x, w0);
        fma4(acc[m], xv.y, w1);
        fma4(acc[m], xv.z, w2);
        fma4(acc[m], xv.w, w3);
      }
    }
    __syncthreads();
  }

#pragma unroll
  for (int m = 0; m < 4; m++) {
    int r = row0 + rg + (m << 6);
    if (r < N) {
      float di = dinv[r];
      acc[m].x *= di; acc[m].y *= di; acc[m].z *= di; acc[m].w *= di;
      *(float4*)&h1s[(size_t)r * HID + (jq << 2)] = acc[m];
    }
  }
}

// ===== layer1 aggregation + relu + W2, fused. 16 lanes per node. =====
__global__ __launch_bounds__(256) void k_agg1f(const int* __restrict__ rowbeg,
                                               const int* __restrict__ rowend,
                                               const int* __restrict__ csr,
                                               const float* __restrict__ h1s,
                                               const float* __restrict__ dinv,
                                               const float* __restrict__ b1,
                                               const float* __restrict__ W2,
                                               float* __restrict__ h2s, int N) {
  const int f = threadIdx.x & 15;
  const int node = blockIdx.x * 16 + (threadIdx.x >> 4);
  if (node >= N) return;
  int j = rowbeg[node];
  const int end = rowend[node];
  float acc = h1s[(size_t)node * HID + f];  // self loop (pre-scaled)
  for (; j < end && (j & 3); ++j) acc += h1s[(size_t)csr[j] * HID + f];
  for (; j + 4 <= end; j += 4) {
    int4 ss = *(const int4*)&csr[j];  // broadcast within group
    float a0 = h1s[(size_t)ss.x * HID + f];
    float a1 = h1s[(size_t)ss.y * HID + f];
    float a2 = h1s[(size_t)ss.z * HID + f];
    float a3 = h1s[(size_t)ss.w * HID + f];
    acc += (a0 + a1) + (a2 + a3);
  }
  for (; j < end; ++j) acc += h1s[(size_t)csr[j] * HID + f];

  float di = dinv[node];
  float v = fmaxf(acc * di + b1[f], 0.f);
  float o0 = v * W2[f * 2 + 0];
  float o1 = v * W2[f * 2 + 1];
#pragma unroll
  for (int d = 1; d < 16; d <<= 1) {
    o0 += __shfl_xor(o0, d);
    o1 += __shfl_xor(o1, d);
  }
  if (f == 0) *(float2*)&h2s[(size_t)node * 2] = make_float2(o0 * di, o1 * di);
}

// ===== layer2 aggregation + bias, fused. thread per node. =====
__global__ __launch_bounds__(256) void k_agg2f(const int* __restrict__ rowbeg,
                                               const int* __restrict__ rowend,
                                               const int* __restrict__ csr,
                                               const float* __restrict__ h2s,
                                               const float* __restrict__ dinv,
                                               const float* __restrict__ b2,
                                               float* __restrict__ out, int N) {
  int i = blockIdx.x * 256 + threadIdx.x;
  if (i >= N) return;
  int j = rowbeg[i];
  const int end = rowend[i];
  float2 o = *(const float2*)&h2s[(size_t)i * 2];  // self loop
  for (; j < end && (j & 3); ++j) {
    float2 v = *(const float2*)&h2s[(size_t)csr[j] * 2];
    o.x += v.x; o.y += v.y;
  }
  for (; j + 4 <= end; j += 4) {
    int4 ss = *(const int4*)&csr[j];
    float2 v0 = *(const float2*)&h2s[(size_t)ss.x * 2];
    float2 v1 = *(const float2*)&h2s[(size_t)ss.y * 2];
    float2 v2 = *(const float2*)&h2s[(size_t)ss.z * 2];
    float2 v3 = *(const float2*)&h2s[(size_t)ss.w * 2];
    o.x += (v0.x + v1.x) + (v2.x + v3.x);
    o.y += (v0.y + v1.y) + (v2.y + v3.y);
  }
  for (; j < end; ++j) {
    float2 v = *(const float2*)&h2s[(size_t)csr[j] * 2];
    o.x += v.x; o.y += v.y;
  }
  float di = dinv[i];
  o.x = o.x * di + b2[0];
  o.y = o.y * di + b2[1];
  *(float2*)&out[(size_t)i * 2] = o;
}

// ================= launch =================
extern "C" void kernel_launch(void* const* d_in, const int* in_sizes, int n_in,
                              void* d_out, int out_size, void* d_ws, size_t ws_size,
                              hipStream_t stream) {
  const float* x = (const float*)d_in[0];
  const int* ei = (const int*)d_in[1];  // harness delivers integer inputs as int32
  const float* W1 = (const float*)d_in[2];
  const float* b1 = (const float*)d_in[3];
  const float* W2 = (const float*)d_in[4];
  const float* b2 = (const float*)d_in[5];
  float* out = (float*)d_out;
  const int N = in_sizes[0] / NFEAT;
  const int E = in_sizes[1] / 2;
  const int nb = (N + 255) / 256;  // buckets of 256 nodes

  // workspace: cnt_t/off_t[MAXNB*NBLK], gcnt/gbase[MAXNB], binned[E+pad],
  //            csr[E+pad], rowbeg[N], rowend[N] (ints);
  //            dinv[N], h1s[16N], h2s[2N] (floats)  ~37 MB
  char* p = (char*)d_ws;
  int* cnt_t = (int*)p;    p += (size_t)MAXNB * NBLK * 4;
  int* off_t = (int*)p;    p += (size_t)MAXNB * NBLK * 4;
  int* gcnt = (int*)p;     p += (size_t)MAXNB * 4;
  int* gbase = (int*)p;    p += (size_t)MAXNB * 4;
  int* binned = (int*)p;   p += ((size_t)E + MAXNB * 16) * 4;
  int* csr = (int*)p;      p += ((size_t)E + MAXNB * 16) * 4;
  int* rowbeg = (int*)p;   p += (size_t)N * 4;
  int* rowend = (int*)p;   p += (size_t)N * 4;
  float* dinv = (float*)p; p += (size_t)N * 4;
  float* h1s = (float*)p;  p += (size_t)N * HID * 4;
  float* h2s = (float*)p;  p += (size_t)N * 2 * 4;

  k_hist2d<<<NBLK, 512, 0, stream>>>(ei, cnt_t, E, nb);
  k_colscan<<<nb, 64, 0, stream>>>(cnt_t, off_t, gcnt, nb);
  k_bscan<<<1, 512, 0, stream>>>(gcnt, gbase, nb);
  k_scatter2<<<NBLK, 512, 0, stream>>>(ei, gbase, off_t, binned, E, nb);
  k_sortbucket<<<nb, 256, 0, stream>>>(gbase, gcnt, binned, csr, rowbeg, rowend, dinv, N);
  k_gemm1<<<(N + 255) / 256, 256, 0, stream>>>(x, W1, dinv, h1s, N);
  k_agg1f<<<(N + 15) / 16, 256, 0, stream>>>(rowbeg, rowend, csr, h1s, dinv, b1, W2, h2s, N);
  k_agg2f<<<(N + 255) / 256, 256, 0, stream>>>(rowbeg, rowend, csr, h2s, dinv, b2, out, N);
}

// Round 8
// 221.839 us; speedup vs baseline: 3.1806x; 1.1016x over previous
//
#include <hip/hip_runtime.h>

#define NFEAT 512
#define HID 16
#define MAXNB 512          // max buckets (N/256 = 391 for N=100K)
#define NBLK 256           // blocks for hist/scatter passes (chunking must match)
#define PACK_SHIFT 17      // src fits in 17 bits (N < 131072)
#define PACK_MASK ((1 << PACK_SHIFT) - 1)

// ============ pass A: per-(block,bucket) histogram ============
__global__ __launch_bounds__(512) void k_hist2d(const int* __restrict__ ei,
                                                int* __restrict__ cnt_t,
                                                int E, int nb) {
  __shared__ int l[MAXNB];
  for (int i = threadIdx.x; i < nb; i += 512) l[i] = 0;
  __syncthreads();
  int chunk = (E + NBLK - 1) / NBLK;
  int beg = blockIdx.x * chunk;
  int end = beg + chunk; if (end > E) end = E;
  for (int e = beg + threadIdx.x; e < end; e += 512)
    atomicAdd(&l[ei[(size_t)E + e] >> 8], 1);
  __syncthreads();
  for (int b = threadIdx.x; b < nb; b += 512)
    cnt_t[(size_t)b * NBLK + blockIdx.x] = l[b];
}

// ============ per-bucket column scan (one wave per bucket) ============
__global__ __launch_bounds__(64) void k_colscan(const int* __restrict__ cnt_t,
                                                int* __restrict__ off_t,
                                                int* __restrict__ gcnt, int nb) {
  int b = blockIdx.x;
  if (b >= nb) return;
  int lane = threadIdx.x;
  int4 v = *(const int4*)&cnt_t[(size_t)b * NBLK + lane * 4];
  int tot = v.x + v.y + v.z + v.w;
  int s = tot;
  for (int d = 1; d < 64; d <<= 1) {
    int o = __shfl_up(s, d);
    if (lane >= d) s += o;
  }
  int excl = s - tot;
  int4 w;
  w.x = excl;
  w.y = excl + v.x;
  w.z = excl + v.x + v.y;
  w.w = excl + v.x + v.y + v.z;
  *(int4*)&off_t[(size_t)b * NBLK + lane * 4] = w;
  if (lane == 63) gcnt[b] = s;
}

// ============ scan: 16-aligned bucket bases ============
__global__ __launch_bounds__(512) void k_bscan(const int* __restrict__ gcnt,
                                               int* __restrict__ gbase, int nb) {
  __shared__ int sm[512];
  int t = threadIdx.x;
  int c = (t < nb) ? gcnt[t] : 0;
  int pc = (c + 15) & ~15;
  sm[t] = pc;
  __syncthreads();
  for (int off = 1; off < 512; off <<= 1) {
    int x = (t >= off) ? sm[t - off] : 0;
    __syncthreads();
    sm[t] += x;
    __syncthreads();
  }
  if (t < nb) gbase[t] = sm[t] - pc;
}

// ============ pass B: scatter with precomputed deterministic offsets ============
__global__ __launch_bounds__(512) void k_scatter2(const int* __restrict__ ei,
                                                  const int* __restrict__ gbase,
                                                  const int* __restrict__ off_t,
                                                  int* __restrict__ binned,
                                                  int E, int nb) {
  __shared__ int cur[MAXNB];
  for (int b = threadIdx.x; b < nb; b += 512)
    cur[b] = gbase[b] + off_t[(size_t)b * NBLK + blockIdx.x];
  __syncthreads();
  int chunk = (E + NBLK - 1) / NBLK;
  int beg = blockIdx.x * chunk;
  int end = beg + chunk; if (end > E) end = E;
  for (int e = beg + threadIdx.x; e < end; e += 512) {
    int s = ei[e];
    int d = ei[(size_t)E + e];
    int b = d >> 8;
    int pos = atomicAdd(&cur[b], 1);
    binned[pos] = s | ((d & 255) << PACK_SHIFT);
  }
}

// ============ per-bucket sort -> per-node CSR + dinv ============
__global__ __launch_bounds__(256) void k_sortbucket(const int* __restrict__ gbase,
                                                    const int* __restrict__ gcnt,
                                                    const int* __restrict__ binned,
                                                    int* __restrict__ csr,
                                                    int* __restrict__ rowbeg,
                                                    int* __restrict__ rowend,
                                                    float* __restrict__ dinv, int N) {
  __shared__ int hist[256];
  __shared__ int sm[256];
  __shared__ int cur[256];
  const int t = threadIdx.x;
  const int b = blockIdx.x;
  const int base = gbase[b], cnt = gcnt[b];
  hist[t] = 0;
  __syncthreads();
  for (int j = base + t; j < base + cnt; j += 256)
    atomicAdd(&hist[binned[j] >> PACK_SHIFT], 1);
  __syncthreads();
  int h = hist[t];
  sm[t] = h;
  __syncthreads();
  for (int off = 1; off < 256; off <<= 1) {
    int x = (t >= off) ? sm[t - off] : 0;
    __syncthreads();
    sm[t] += x;
    __syncthreads();
  }
  int incl = sm[t];
  int excl = incl - h;
  cur[t] = excl;
  int node = b * 256 + t;
  if (node < N) {
    rowbeg[node] = base + excl;
    rowend[node] = base + incl;
    dinv[node] = rsqrtf((float)h + 1.0f);
  }
  __syncthreads();
  for (int j = base + t; j < base + cnt; j += 256) {
    int val = binned[j];
    int pos = atomicAdd(&cur[val >> PACK_SHIFT], 1);
    csr[base + pos] = val & PACK_MASK;
  }
}

// ============ GEMM1: h1s = (x @ W1) * dinv[row] ============
// 128-row tiles -> 782 blocks (3.05/CU), LDS 42KB -> 3 blocks/CU resident.
// Thread t: jq = t&3 (4 output cols), rg = t>>2; rows rg, rg+64.
#define BM 128
#define KC 16
#define NC (NFEAT / KC)
#define XPAD 20

__device__ __forceinline__ void fma4(float4& a, float s, const float4& b) {
  a.x += s * b.x;
  a.y += s * b.y;
  a.z += s * b.z;
  a.w += s * b.w;
}

__global__ __launch_bounds__(256) void k_gemm1(const float* __restrict__ x,
                                               const float* __restrict__ W,
                                               const float* __restrict__ dinv,
                                               float* __restrict__ h1s, int N) {
  __shared__ float sW[NFEAT * HID];  // 32 KB
  __shared__ float sx[BM][XPAD];     // 10 KB
  float4* sW4 = (float4*)sW;
  const float4* W4 = (const float4*)W;
  for (int i = threadIdx.x; i < NFEAT * HID / 4; i += 256) sW4[i] = W4[i];

  const float4* x4 = (const float4*)x;
  const int row0 = blockIdx.x * BM;
  const int Nm1 = N - 1;
  const int jq = threadIdx.x & 3;
  const int rg = threadIdx.x >> 2;

  float4 acc[2];
#pragma unroll
  for (int m = 0; m < 2; m++) acc[m] = make_float4(0.f, 0.f, 0.f, 0.f);

  float4 ld[2];
  // preload chunk 0: 128 rows x 16 k = 512 float4, 2 per thread
#pragma unroll
  for (int i = 0; i < 2; i++) {
    int f = threadIdx.x + (i << 8);
    int r = f >> 2, k4 = f & 3;
    int rr = row0 + r; if (rr > Nm1) rr = Nm1;
    ld[i] = x4[(size_t)rr * (NFEAT / 4) + k4];
  }

  for (int c = 0; c < NC; ++c) {
#pragma unroll
    for (int i = 0; i < 2; i++) {
      int f = threadIdx.x + (i << 8);
      int r = f >> 2, k4 = f & 3;
      *(float4*)&sx[r][k4 << 2] = ld[i];
    }
    __syncthreads();
    if (c + 1 < NC) {
#pragma unroll
      for (int i = 0; i < 2; i++) {
        int f = threadIdx.x + (i << 8);
        int r = f >> 2, k4 = f & 3;
        int rr = row0 + r; if (rr > Nm1) rr = Nm1;
        ld[i] = x4[(size_t)rr * (NFEAT / 4) + (c + 1) * (KC / 4) + k4];
      }
    }
#pragma unroll
    for (int q = 0; q < KC / 4; q++) {
      int k0 = c * KC + q * 4;
      float4 w0 = sW4[(k0 + 0) * 4 + jq];
      float4 w1 = sW4[(k0 + 1) * 4 + jq];
      float4 w2 = sW4[(k0 + 2) * 4 + jq];
      float4 w3 = sW4[(k0 + 3) * 4 + jq];
#pragma unroll
      for (int m = 0; m < 2; m++) {
        float4 xv = *(const float4*)&sx[rg + (m << 6)][q << 2];
        fma4(acc[m], xv.x, w0);
        fma4(acc[m], xv.y, w1);
        fma4(acc[m], xv.z, w2);
        fma4(acc[m], xv.w, w3);
      }
    }
    __syncthreads();
  }

#pragma unroll
  for (int m = 0; m < 2; m++) {
    int r = row0 + rg + (m << 6);
    if (r < N) {
      float di = dinv[r];
      acc[m].x *= di; acc[m].y *= di; acc[m].z *= di; acc[m].w *= di;
      *(float4*)&h1s[(size_t)r * HID + (jq << 2)] = acc[m];
    }
  }
}

// ===== layer1 aggregation + relu + W2, fused. 16 lanes per node. =====
__global__ __launch_bounds__(256) void k_agg1f(const int* __restrict__ rowbeg,
                                               const int* __restrict__ rowend,
                                               const int* __restrict__ csr,
                                               const float* __restrict__ h1s,
                                               const float* __restrict__ dinv,
                                               const float* __restrict__ b1,
                                               const float* __restrict__ W2,
                                               float* __restrict__ h2s, int N) {
  const int f = threadIdx.x & 15;
  const int node = blockIdx.x * 16 + (threadIdx.x >> 4);
  if (node >= N) return;
  int j = rowbeg[node];
  const int end = rowend[node];
  float acc = h1s[(size_t)node * HID + f];  // self loop (pre-scaled)
  for (; j < end && (j & 3); ++j) acc += h1s[(size_t)csr[j] * HID + f];
  for (; j + 4 <= end; j += 4) {
    int4 ss = *(const int4*)&csr[j];  // broadcast within group
    float a0 = h1s[(size_t)ss.x * HID + f];
    float a1 = h1s[(size_t)ss.y * HID + f];
    float a2 = h1s[(size_t)ss.z * HID + f];
    float a3 = h1s[(size_t)ss.w * HID + f];
    acc += (a0 + a1) + (a2 + a3);
  }
  for (; j < end; ++j) acc += h1s[(size_t)csr[j] * HID + f];

  float di = dinv[node];
  float v = fmaxf(acc * di + b1[f], 0.f);
  float o0 = v * W2[f * 2 + 0];
  float o1 = v * W2[f * 2 + 1];
#pragma unroll
  for (int d = 1; d < 16; d <<= 1) {
    o0 += __shfl_xor(o0, d);
    o1 += __shfl_xor(o1, d);
  }
  if (f == 0) *(float2*)&h2s[(size_t)node * 2] = make_float2(o0 * di, o1 * di);
}

// ===== layer2 aggregation + bias, fused. thread per node. =====
__global__ __launch_bounds__(256) void k_agg2f(const int* __restrict__ rowbeg,
                                               const int* __restrict__ rowend,
                                               const int* __restrict__ csr,
                                               const float* __restrict__ h2s,
                                               const float* __restrict__ dinv,
                                               const float* __restrict__ b2,
                                               float* __restrict__ out, int N) {
  int i = blockIdx.x * 256 + threadIdx.x;
  if (i >= N) return;
  int j = rowbeg[i];
  const int end = rowend[i];
  float2 o = *(const float2*)&h2s[(size_t)i * 2];  // self loop
  for (; j < end && (j & 3); ++j) {
    float2 v = *(const float2*)&h2s[(size_t)csr[j] * 2];
    o.x += v.x; o.y += v.y;
  }
  for (; j + 4 <= end; j += 4) {
    int4 ss = *(const int4*)&csr[j];
    float2 v0 = *(const float2*)&h2s[(size_t)ss.x * 2];
    float2 v1 = *(const float2*)&h2s[(size_t)ss.y * 2];
    float2 v2 = *(const float2*)&h2s[(size_t)ss.z * 2];
    float2 v3 = *(const float2*)&h2s[(size_t)ss.w * 2];
    o.x += (v0.x + v1.x) + (v2.x + v3.x);
    o.y += (v0.y + v1.y) + (v2.y + v3.y);
  }
  for (; j < end; ++j) {
    float2 v = *(const float2*)&h2s[(size_t)csr[j] * 2];
    o.x += v.x; o.y += v.y;
  }
  float di = dinv[i];
  o.x = o.x * di + b2[0];
  o.y = o.y * di + b2[1];
  *(float2*)&out[(size_t)i * 2] = o;
}

// ================= launch =================
extern "C" void kernel_launch(void* const* d_in, const int* in_sizes, int n_in,
                              void* d_out, int out_size, void* d_ws, size_t ws_size,
                              hipStream_t stream) {
  const float* x = (const float*)d_in[0];
  const int* ei = (const int*)d_in[1];  // harness delivers integer inputs as int32
  const float* W1 = (const float*)d_in[2];
  const float* b1 = (const float*)d_in[3];
  const float* W2 = (const float*)d_in[4];
  const float* b2 = (const float*)d_in[5];
  float* out = (float*)d_out;
  const int N = in_sizes[0] / NFEAT;
  const int E = in_sizes[1] / 2;
  const int nb = (N + 255) / 256;  // buckets of 256 nodes

  char* p = (char*)d_ws;
  int* cnt_t = (int*)p;    p += (size_t)MAXNB * NBLK * 4;
  int* off_t = (int*)p;    p += (size_t)MAXNB * NBLK * 4;
  int* gcnt = (int*)p;     p += (size_t)MAXNB * 4;
  int* gbase = (int*)p;    p += (size_t)MAXNB * 4;
  int* binned = (int*)p;   p += ((size_t)E + MAXNB * 16) * 4;
  int* csr = (int*)p;      p += ((size_t)E + MAXNB * 16) * 4;
  int* rowbeg = (int*)p;   p += (size_t)N * 4;
  int* rowend = (int*)p;   p += (size_t)N * 4;
  float* dinv = (float*)p; p += (size_t)N * 4;
  float* h1s = (float*)p;  p += (size_t)N * HID * 4;
  float* h2s = (float*)p;  p += (size_t)N * 2 * 4;

  k_hist2d<<<NBLK, 512, 0, stream>>>(ei, cnt_t, E, nb);
  k_colscan<<<nb, 64, 0, stream>>>(cnt_t, off_t, gcnt, nb);
  k_bscan<<<1, 512, 0, stream>>>(gcnt, gbase, nb);
  k_scatter2<<<NBLK, 512, 0, stream>>>(ei, gbase, off_t, binned, E, nb);
  k_sortbucket<<<nb, 256, 0, stream>>>(gbase, gcnt, binned, csr, rowbeg, rowend, dinv, N);
  k_gemm1<<<(N + BM - 1) / BM, 256, 0, stream>>>(x, W1, dinv, h1s, N);
  k_agg1f<<<(N + 15) / 16, 256, 0, stream>>>(rowbeg, rowend, csr, h1s, dinv, b1, W2, h2s, N);
  k_agg2f<<<(N + 255) / 256, 256, 0, stream>>>(rowbeg, rowend, csr, h2s, dinv, b2, out, N);
}

// Round 9
// 196.214 us; speedup vs baseline: 3.5960x; 1.1306x over previous
//
#include <hip/hip_runtime.h>

#define NFEAT 512
#define HID 16
#define MAXNB 512          // max buckets (N/256 = 391 for N=100K)
#define NBLK 256           // blocks for hist/scatter passes (chunking must match)
#define PACK_SHIFT 17      // src fits in 17 bits (N < 131072)
#define PACK_MASK ((1 << PACK_SHIFT) - 1)

// ============ pass A: per-(block,bucket) histogram ============
__global__ __launch_bounds__(512) void k_hist2d(const int* __restrict__ ei,
                                                int* __restrict__ cnt_t,
                                                int E, int nb) {
  __shared__ int l[MAXNB];
  for (int i = threadIdx.x; i < nb; i += 512) l[i] = 0;
  __syncthreads();
  int chunk = (E + NBLK - 1) / NBLK;
  int beg = blockIdx.x * chunk;
  int end = beg + chunk; if (end > E) end = E;
  for (int e = beg + threadIdx.x; e < end; e += 512)
    atomicAdd(&l[ei[(size_t)E + e] >> 8], 1);
  __syncthreads();
  for (int b = threadIdx.x; b < nb; b += 512)
    cnt_t[(size_t)b * NBLK + blockIdx.x] = l[b];
}

// ============ per-bucket column scan (one wave per bucket) ============
__global__ __launch_bounds__(64) void k_colscan(const int* __restrict__ cnt_t,
                                                int* __restrict__ off_t,
                                                int* __restrict__ gcnt, int nb) {
  int b = blockIdx.x;
  if (b >= nb) return;
  int lane = threadIdx.x;
  int4 v = *(const int4*)&cnt_t[(size_t)b * NBLK + lane * 4];
  int tot = v.x + v.y + v.z + v.w;
  int s = tot;
  for (int d = 1; d < 64; d <<= 1) {
    int o = __shfl_up(s, d);
    if (lane >= d) s += o;
  }
  int excl = s - tot;
  int4 w;
  w.x = excl;
  w.y = excl + v.x;
  w.z = excl + v.x + v.y;
  w.w = excl + v.x + v.y + v.z;
  *(int4*)&off_t[(size_t)b * NBLK + lane * 4] = w;
  if (lane == 63) gcnt[b] = s;
}

// ============ scan: 16-aligned bucket bases ============
__global__ __launch_bounds__(512) void k_bscan(const int* __restrict__ gcnt,
                                               int* __restrict__ gbase, int nb) {
  __shared__ int sm[512];
  int t = threadIdx.x;
  int c = (t < nb) ? gcnt[t] : 0;
  int pc = (c + 15) & ~15;
  sm[t] = pc;
  __syncthreads();
  for (int off = 1; off < 512; off <<= 1) {
    int x = (t >= off) ? sm[t - off] : 0;
    __syncthreads();
    sm[t] += x;
    __syncthreads();
  }
  if (t < nb) gbase[t] = sm[t] - pc;
}

// ============ pass B: scatter with precomputed deterministic offsets ============
__global__ __launch_bounds__(512) void k_scatter2(const int* __restrict__ ei,
                                                  const int* __restrict__ gbase,
                                                  const int* __restrict__ off_t,
                                                  int* __restrict__ binned,
                                                  int E, int nb) {
  __shared__ int cur[MAXNB];
  for (int b = threadIdx.x; b < nb; b += 512)
    cur[b] = gbase[b] + off_t[(size_t)b * NBLK + blockIdx.x];
  __syncthreads();
  int chunk = (E + NBLK - 1) / NBLK;
  int beg = blockIdx.x * chunk;
  int end = beg + chunk; if (end > E) end = E;
  for (int e = beg + threadIdx.x; e < end; e += 512) {
    int s = ei[e];
    int d = ei[(size_t)E + e];
    int b = d >> 8;
    int pos = atomicAdd(&cur[b], 1);
    binned[pos] = s | ((d & 255) << PACK_SHIFT);
  }
}

// ============ per-bucket sort -> per-node CSR + dinv ============
__global__ __launch_bounds__(256) void k_sortbucket(const int* __restrict__ gbase,
                                                    const int* __restrict__ gcnt,
                                                    const int* __restrict__ binned,
                                                    int* __restrict__ csr,
                                                    int* __restrict__ rowbeg,
                                                    int* __restrict__ rowend,
                                                    float* __restrict__ dinv, int N) {
  __shared__ int hist[256];
  __shared__ int sm[256];
  __shared__ int cur[256];
  const int t = threadIdx.x;
  const int b = blockIdx.x;
  const int base = gbase[b], cnt = gcnt[b];
  hist[t] = 0;
  __syncthreads();
  for (int j = base + t; j < base + cnt; j += 256)
    atomicAdd(&hist[binned[j] >> PACK_SHIFT], 1);
  __syncthreads();
  int h = hist[t];
  sm[t] = h;
  __syncthreads();
  for (int off = 1; off < 256; off <<= 1) {
    int x = (t >= off) ? sm[t - off] : 0;
    __syncthreads();
    sm[t] += x;
    __syncthreads();
  }
  int incl = sm[t];
  int excl = incl - h;
  cur[t] = excl;
  int node = b * 256 + t;
  if (node < N) {
    rowbeg[node] = base + excl;
    rowend[node] = base + incl;
    dinv[node] = rsqrtf((float)h + 1.0f);
  }
  __syncthreads();
  for (int j = base + t; j < base + cnt; j += 256) {
    int val = binned[j];
    int pos = atomicAdd(&cur[val >> PACK_SHIFT], 1);
    csr[base + pos] = val & PACK_MASK;
  }
}

// ============ GEMM1: h1s = (x @ W1) * dinv[row]  — barrier-free streaming ============
// 64 rows/block, 256 thr = 4 waves; wave w owns K-quarter [128w,128w+128).
// Lane = row; each lane streams its row (32 float4, prefetch depth 4); no barriers
// in the K loop. W in LDS, wave-uniform reads (broadcast). One final LDS reduce.
#define GR 64

__device__ __forceinline__ void fma4(float4& a, float s, const float4& b) {
  a.x += s * b.x;
  a.y += s * b.y;
  a.z += s * b.z;
  a.w += s * b.w;
}

__device__ __forceinline__ void dostep(float s, const float4* __restrict__ sW4, int k,
                                       float4& a0, float4& a1, float4& a2, float4& a3) {
  fma4(a0, s, sW4[k * 4 + 0]);
  fma4(a1, s, sW4[k * 4 + 1]);
  fma4(a2, s, sW4[k * 4 + 2]);
  fma4(a3, s, sW4[k * 4 + 3]);
}

__global__ __launch_bounds__(256) void k_gemm1(const float* __restrict__ x,
                                               const float* __restrict__ W,
                                               const float* __restrict__ dinv,
                                               float* __restrict__ h1s, int N) {
  __shared__ float sW[NFEAT * HID];        // 32 KB
  __shared__ float part[4][GR][HID + 4];   // 20 KB, 80B row stride (16B aligned)
  float4* sW4 = (float4*)sW;
  const float4* W4 = (const float4*)W;
  for (int i = threadIdx.x; i < NFEAT * HID / 4; i += 256) sW4[i] = W4[i];
  __syncthreads();

  const int w = threadIdx.x >> 6;     // K-quarter
  const int lane = threadIdx.x & 63;  // row within tile
  int row = blockIdx.x * GR + lane;
  if (row > N - 1) row = N - 1;  // clamp: duplicate work, output guarded
  const float4* xr = (const float4*)(x + (size_t)row * NFEAT) + w * 32;

  float4 a0 = make_float4(0.f, 0.f, 0.f, 0.f), a1 = a0, a2 = a0, a3 = a0;

  float4 xv0 = xr[0], xv1 = xr[1], xv2 = xr[2], xv3 = xr[3];
  const int kbase = w * 128;
#pragma unroll
  for (int g = 0; g < 8; ++g) {
    float4 c0 = xv0, c1 = xv1, c2 = xv2, c3 = xv3;
    if (g < 7) {
      xv0 = xr[g * 4 + 4];
      xv1 = xr[g * 4 + 5];
      xv2 = xr[g * 4 + 6];
      xv3 = xr[g * 4 + 7];
    }
    int k0 = kbase + g * 16;
    dostep(c0.x, sW4, k0 + 0, a0, a1, a2, a3);
    dostep(c0.y, sW4, k0 + 1, a0, a1, a2, a3);
    dostep(c0.z, sW4, k0 + 2, a0, a1, a2, a3);
    dostep(c0.w, sW4, k0 + 3, a0, a1, a2, a3);
    dostep(c1.x, sW4, k0 + 4, a0, a1, a2, a3);
    dostep(c1.y, sW4, k0 + 5, a0, a1, a2, a3);
    dostep(c1.z, sW4, k0 + 6, a0, a1, a2, a3);
    dostep(c1.w, sW4, k0 + 7, a0, a1, a2, a3);
    dostep(c2.x, sW4, k0 + 8, a0, a1, a2, a3);
    dostep(c2.y, sW4, k0 + 9, a0, a1, a2, a3);
    dostep(c2.z, sW4, k0 + 10, a0, a1, a2, a3);
    dostep(c2.w, sW4, k0 + 11, a0, a1, a2, a3);
    dostep(c3.x, sW4, k0 + 12, a0, a1, a2, a3);
    dostep(c3.y, sW4, k0 + 13, a0, a1, a2, a3);
    dostep(c3.z, sW4, k0 + 14, a0, a1, a2, a3);
    dostep(c3.w, sW4, k0 + 15, a0, a1, a2, a3);
  }

  *(float4*)&part[w][lane][0] = a0;
  *(float4*)&part[w][lane][4] = a1;
  *(float4*)&part[w][lane][8] = a2;
  *(float4*)&part[w][lane][12] = a3;
  __syncthreads();

  const int r = threadIdx.x >> 2;
  const int jq = threadIdx.x & 3;
  float4 s0 = *(const float4*)&part[0][r][jq * 4];
  float4 s1 = *(const float4*)&part[1][r][jq * 4];
  float4 s2 = *(const float4*)&part[2][r][jq * 4];
  float4 s3 = *(const float4*)&part[3][r][jq * 4];
  float4 s;
  s.x = (s0.x + s1.x) + (s2.x + s3.x);
  s.y = (s0.y + s1.y) + (s2.y + s3.y);
  s.z = (s0.z + s1.z) + (s2.z + s3.z);
  s.w = (s0.w + s1.w) + (s2.w + s3.w);
  int orow = blockIdx.x * GR + r;
  if (orow < N) {
    float di = dinv[orow];
    s.x *= di; s.y *= di; s.z *= di; s.w *= di;
    *(float4*)&h1s[(size_t)orow * HID + jq * 4] = s;
  }
}

// ===== layer1 aggregation + relu + W2, fused. 16 lanes per node. =====
__global__ __launch_bounds__(256) void k_agg1f(const int* __restrict__ rowbeg,
                                               const int* __restrict__ rowend,
                                               const int* __restrict__ csr,
                                               const float* __restrict__ h1s,
                                               const float* __restrict__ dinv,
                                               const float* __restrict__ b1,
                                               const float* __restrict__ W2,
                                               float* __restrict__ h2s, int N) {
  const int f = threadIdx.x & 15;
  const int node = blockIdx.x * 16 + (threadIdx.x >> 4);
  if (node >= N) return;
  int j = rowbeg[node];
  const int end = rowend[node];
  float acc = h1s[(size_t)node * HID + f];  // self loop (pre-scaled)
  for (; j < end && (j & 3); ++j) acc += h1s[(size_t)csr[j] * HID + f];
  for (; j + 4 <= end; j += 4) {
    int4 ss = *(const int4*)&csr[j];  // broadcast within group
    float a0 = h1s[(size_t)ss.x * HID + f];
    float a1 = h1s[(size_t)ss.y * HID + f];
    float a2 = h1s[(size_t)ss.z * HID + f];
    float a3 = h1s[(size_t)ss.w * HID + f];
    acc += (a0 + a1) + (a2 + a3);
  }
  for (; j < end; ++j) acc += h1s[(size_t)csr[j] * HID + f];

  float di = dinv[node];
  float v = fmaxf(acc * di + b1[f], 0.f);
  float o0 = v * W2[f * 2 + 0];
  float o1 = v * W2[f * 2 + 1];
#pragma unroll
  for (int d = 1; d < 16; d <<= 1) {
    o0 += __shfl_xor(o0, d);
    o1 += __shfl_xor(o1, d);
  }
  if (f == 0) *(float2*)&h2s[(size_t)node * 2] = make_float2(o0 * di, o1 * di);
}

// ===== layer2 aggregation + bias, fused. thread per node. =====
__global__ __launch_bounds__(256) void k_agg2f(const int* __restrict__ rowbeg,
                                               const int* __restrict__ rowend,
                                               const int* __restrict__ csr,
                                               const float* __restrict__ h2s,
                                               const float* __restrict__ dinv,
                                               const float* __restrict__ b2,
                                               float* __restrict__ out, int N) {
  int i = blockIdx.x * 256 + threadIdx.x;
  if (i >= N) return;
  int j = rowbeg[i];
  const int end = rowend[i];
  float2 o = *(const float2*)&h2s[(size_t)i * 2];  // self loop
  for (; j < end && (j & 3); ++j) {
    float2 v = *(const float2*)&h2s[(size_t)csr[j] * 2];
    o.x += v.x; o.y += v.y;
  }
  for (; j + 4 <= end; j += 4) {
    int4 ss = *(const int4*)&csr[j];
    float2 v0 = *(const float2*)&h2s[(size_t)ss.x * 2];
    float2 v1 = *(const float2*)&h2s[(size_t)ss.y * 2];
    float2 v2 = *(const float2*)&h2s[(size_t)ss.z * 2];
    float2 v3 = *(const float2*)&h2s[(size_t)ss.w * 2];
    o.x += (v0.x + v1.x) + (v2.x + v3.x);
    o.y += (v0.y + v1.y) + (v2.y + v3.y);
  }
  for (; j < end; ++j) {
    float2 v = *(const float2*)&h2s[(size_t)csr[j] * 2];
    o.x += v.x; o.y += v.y;
  }
  float di = dinv[i];
  o.x = o.x * di + b2[0];
  o.y = o.y * di + b2[1];
  *(float2*)&out[(size_t)i * 2] = o;
}

// ================= launch =================
extern "C" void kernel_launch(void* const* d_in, const int* in_sizes, int n_in,
                              void* d_out, int out_size, void* d_ws, size_t ws_size,
                              hipStream_t stream) {
  const float* x = (const float*)d_in[0];
  const int* ei = (const int*)d_in[1];  // harness delivers integer inputs as int32
  const float* W1 = (const float*)d_in[2];
  const float* b1 = (const float*)d_in[3];
  const float* W2 = (const float*)d_in[4];
  const float* b2 = (const float*)d_in[5];
  float* out = (float*)d_out;
  const int N = in_sizes[0] / NFEAT;
  const int E = in_sizes[1] / 2;
  const int nb = (N + 255) / 256;  // buckets of 256 nodes

  char* p = (char*)d_ws;
  int* cnt_t = (int*)p;    p += (size_t)MAXNB * NBLK * 4;
  int* off_t = (int*)p;    p += (size_t)MAXNB * NBLK * 4;
  int* gcnt = (int*)p;     p += (size_t)MAXNB * 4;
  int* gbase = (int*)p;    p += (size_t)MAXNB * 4;
  int* binned = (int*)p;   p += ((size_t)E + MAXNB * 16) * 4;
  int* csr = (int*)p;      p += ((size_t)E + MAXNB * 16) * 4;
  int* rowbeg = (int*)p;   p += (size_t)N * 4;
  int* rowend = (int*)p;   p += (size_t)N * 4;
  float* dinv = (float*)p; p += (size_t)N * 4;
  float* h1s = (float*)p;  p += (size_t)N * HID * 4;
  float* h2s = (float*)p;  p += (size_t)N * 2 * 4;

  k_hist2d<<<NBLK, 512, 0, stream>>>(ei, cnt_t, E, nb);
  k_colscan<<<nb, 64, 0, stream>>>(cnt_t, off_t, gcnt, nb);
  k_bscan<<<1, 512, 0, stream>>>(gcnt, gbase, nb);
  k_scatter2<<<NBLK, 512, 0, stream>>>(ei, gbase, off_t, binned, E, nb);
  k_sortbucket<<<nb, 256, 0, stream>>>(gbase, gcnt, binned, csr, rowbeg, rowend, dinv, N);
  k_gemm1<<<(N + GR - 1) / GR, 256, 0, stream>>>(x, W1, dinv, h1s, N);
  k_agg1f<<<(N + 15) / 16, 256, 0, stream>>>(rowbeg, rowend, csr, h1s, dinv, b1, W2, h2s, N);
  k_agg2f<<<(N + 255) / 256, 256, 0, stream>>>(rowbeg, rowend, csr, h2s, dinv, b2, out, N);
}